// Round 1
// baseline (88.179 us; speedup 1.0000x reference)
//
#include <hip/hip_runtime.h>
#include <hip/hip_bf16.h>
#include <stdint.h>

// Problem constants (fixed by the reference)
#define M_ROWS 4096   // B
#define N_COLS 8192   // N
#define KDIM   512    // D

// GEMM tile (m97 structure: 128x128 tile, BK=64, 4 waves, 16x16x32 bf16 MFMA)
#define BM 128
#define BN 128
#define BK 64

typedef __attribute__((ext_vector_type(8))) __bf16 bf16x8;
typedef __attribute__((ext_vector_type(4))) float  f32x4;

// ---------- fp32 -> bf16 (RNE), vectorized ----------
__device__ __forceinline__ unsigned short f2bf(float f) {
  union { float f; uint32_t u; } v; v.f = f;
  uint32_t u = v.u;
  u += 0x7fffu + ((u >> 16) & 1u);   // round-to-nearest-even; inputs finite
  return (unsigned short)(u >> 16);
}

__global__ void cvt_bf16_kernel(const float* __restrict__ in,
                                unsigned short* __restrict__ out, int n4) {
  int i = blockIdx.x * blockDim.x + threadIdx.x;
  if (i < n4) {
    float4 v = reinterpret_cast<const float4*>(in)[i];
    ushort4 o;
    o.x = f2bf(v.x); o.y = f2bf(v.y); o.z = f2bf(v.z); o.w = f2bf(v.w);
    reinterpret_cast<ushort4*>(out)[i] = o;
  }
}

// ---------- find positive index per row + fp32 dot (s_pos) ----------
// one block per anchor row; scans 8192 int32 one-hot entries (int4-vectorized)
__global__ void pos_dot_kernel(const float* __restrict__ A,
                               const float* __restrict__ S,
                               const int* __restrict__ onehot,
                               float* __restrict__ s_pos) {
  const int b = blockIdx.x;
  __shared__ int pos_s;
  if (threadIdx.x == 0) pos_s = 0;
  __syncthreads();

  const int4* row = reinterpret_cast<const int4*>(onehot + (size_t)b * N_COLS);
  for (int i = threadIdx.x; i < N_COLS / 4; i += blockDim.x) {
    int4 v = row[i];
    if (v.x | v.y | v.z | v.w) {
      int j = i * 4 + (v.x ? 0 : (v.y ? 1 : (v.z ? 2 : 3)));
      pos_s = j;  // exactly one nonzero per row -> single writer
    }
  }
  __syncthreads();
  const int j = pos_s;

  float sum = 0.f;
  const float* a = A + (size_t)b * KDIM;
  const float* s = S + (size_t)j * KDIM;
  for (int d = threadIdx.x; d < KDIM; d += blockDim.x) sum += a[d] * s[d];
  #pragma unroll
  for (int off = 32; off > 0; off >>= 1) sum += __shfl_down(sum, off, 64);

  __shared__ float wsum[4];
  const int wid = threadIdx.x >> 6, lane = threadIdx.x & 63;
  if (lane == 0) wsum[wid] = sum;
  __syncthreads();
  if (threadIdx.x == 0) s_pos[b] = (wsum[0] + wsum[1]) + (wsum[2] + wsum[3]);
}

// ---------- bf16 MFMA GEMM with fused hinge-sum epilogue ----------
// A[M,K] row-major, S[N,K] row-major (i.e. B^T input layout): both K-contiguous.
// Each block: 128x128 output tile; 4 waves in 2x2; each wave 64x64 = 4x4 frags.
__global__ __launch_bounds__(256) void gemm_hinge_kernel(
    const unsigned short* __restrict__ Abf,
    const unsigned short* __restrict__ Sbf,
    const float* __restrict__ s_pos,
    double* __restrict__ partial) {
  __shared__ alignas(16) unsigned short As[BM * BK];
  __shared__ alignas(16) unsigned short Bs[BN * BK];
  __shared__ float wred[4];

  const int t    = threadIdx.x;
  const int wid  = t >> 6;
  const int lane = t & 63;
  const int wr   = wid >> 1, wc = wid & 1;
  const int rowBase = blockIdx.x * BM;
  const int colBase = blockIdx.y * BN;

  f32x4 acc[4][4];
  #pragma unroll
  for (int m = 0; m < 4; ++m)
    #pragma unroll
    for (int n = 0; n < 4; ++n)
      acc[m][n] = (f32x4){0.f, 0.f, 0.f, 0.f};

  const unsigned short* Ag = Abf + (size_t)rowBase * KDIM;
  const unsigned short* Bg = Sbf + (size_t)colBase * KDIM;
  const int rr = t >> 3;         // 0..31: row within 32-row staging slab
  const int kc = (t & 7) * 8;    // 0..56: k element offset (16B granules)

  for (int kt = 0; kt < KDIM / BK; ++kt) {
    const int k0 = kt * BK;
    // stage A-tile and B-tile: 4 slabs of 32 rows each, 16B/lane direct-to-LDS
    #pragma unroll
    for (int c = 0; c < 4; ++c) {
      const unsigned short* srcA = Ag + (size_t)(c * 32 + rr) * KDIM + k0 + kc;
      const unsigned short* srcB = Bg + (size_t)(c * 32 + rr) * KDIM + k0 + kc;
      __builtin_amdgcn_global_load_lds(
          (const __attribute__((address_space(1))) void*)srcA,
          (__attribute__((address_space(3))) void*)(As + c * 2048 + wid * 512),
          16, 0, 0);
      __builtin_amdgcn_global_load_lds(
          (const __attribute__((address_space(1))) void*)srcB,
          (__attribute__((address_space(3))) void*)(Bs + c * 2048 + wid * 512),
          16, 0, 0);
    }
    __syncthreads();   // compiler drains vmcnt before barrier

    #pragma unroll
    for (int kk = 0; kk < 2; ++kk) {
      bf16x8 af[4], bfv[4];
      const int krd = kk * 32 + (lane >> 4) * 8;
      #pragma unroll
      for (int m = 0; m < 4; ++m)
        af[m] = *(const bf16x8*)&As[(wr * 64 + m * 16 + (lane & 15)) * BK + krd];
      #pragma unroll
      for (int n = 0; n < 4; ++n)
        bfv[n] = *(const bf16x8*)&Bs[(wc * 64 + n * 16 + (lane & 15)) * BK + krd];
      #pragma unroll
      for (int m = 0; m < 4; ++m)
        #pragma unroll
        for (int n = 0; n < 4; ++n)
          acc[m][n] = __builtin_amdgcn_mfma_f32_16x16x32_bf16(af[m], bfv[n],
                                                              acc[m][n], 0, 0, 0);
    }
    __syncthreads();
  }

  // Epilogue: hinge = max(s - s_pos[row] + 1, 0), summed to one scalar/block.
  // C/D layout (verified m89): col = lane&15, row = (lane>>4)*4 + reg.
  float lsum = 0.f;
  const int rl = (lane >> 4) * 4;
  #pragma unroll
  for (int m = 0; m < 4; ++m) {
    float sp[4];
    #pragma unroll
    for (int r = 0; r < 4; ++r)
      sp[r] = s_pos[rowBase + wr * 64 + m * 16 + rl + r];
    #pragma unroll
    for (int n = 0; n < 4; ++n)
      #pragma unroll
      for (int r = 0; r < 4; ++r) {
        float h = acc[m][n][r] - sp[r] + 1.0f;
        lsum += fmaxf(h, 0.f);
      }
  }
  #pragma unroll
  for (int off = 32; off > 0; off >>= 1) lsum += __shfl_down(lsum, off, 64);
  if (lane == 0) wred[wid] = lsum;
  __syncthreads();
  if (t == 0)
    partial[blockIdx.y * gridDim.x + blockIdx.x] =
        (double)((wred[0] + wred[1]) + (wred[2] + wred[3]));
}

// ---------- deterministic final reduction ----------
__global__ void finalize_kernel(const double* __restrict__ partial,
                                float* __restrict__ out) {
  __shared__ double sdata[256];
  double s = 0.0;
  for (int i = threadIdx.x; i < (M_ROWS / BM) * (N_COLS / BN); i += 256)
    s += partial[i];
  sdata[threadIdx.x] = s;
  __syncthreads();
  for (int st = 128; st > 0; st >>= 1) {
    if (threadIdx.x < st) sdata[threadIdx.x] += sdata[threadIdx.x + st];
    __syncthreads();
  }
  if (threadIdx.x == 0) {
    // positive entry contributes exactly ~1 per row -> subtract B
    double v = (sdata[0] - (double)M_ROWS) / ((double)M_ROWS * (double)(N_COLS - 1));
    *out = (float)v;
  }
}

extern "C" void kernel_launch(void* const* d_in, const int* in_sizes, int n_in,
                              void* d_out, int out_size, void* d_ws, size_t ws_size,
                              hipStream_t stream) {
  const float* A  = (const float*)d_in[0];   // anchor [4096,512] f32
  const float* S  = (const float*)d_in[1];   // sample [8192,512] f32
  const int*   oh = (const int*)d_in[2];     // one-hot [4096,8192] int
  float* out = (float*)d_out;

  // workspace layout (~12.1 MB): partials | s_pos | A_bf16 | S_bf16
  char* ws = (char*)d_ws;
  double* partial = (double*)ws;                           // 2048 * 8B = 16KB
  float* s_pos    = (float*)(ws + 16384);                  // 4096 * 4B = 16KB
  unsigned short* Abf = (unsigned short*)(ws + 32768);     // 4 MB
  unsigned short* Sbf = Abf + (size_t)M_ROWS * KDIM;       // 8 MB

  const int nA4 = M_ROWS * KDIM / 4;
  const int nS4 = N_COLS * KDIM / 4;
  cvt_bf16_kernel<<<(nA4 + 255) / 256, 256, 0, stream>>>(A, Abf, nA4);
  cvt_bf16_kernel<<<(nS4 + 255) / 256, 256, 0, stream>>>(S, Sbf, nS4);
  pos_dot_kernel<<<M_ROWS, 256, 0, stream>>>(A, S, oh, s_pos);

  dim3 grid(M_ROWS / BM, N_COLS / BN);  // 32 x 64
  gemm_hinge_kernel<<<grid, 256, 0, stream>>>(Abf, Sbf, s_pos, partial);
  finalize_kernel<<<1, 256, 0, stream>>>(partial, out);
}

// Round 2
// 70.178 us; speedup vs baseline: 1.2565x; 1.2565x over previous
//
#include <hip/hip_runtime.h>
#include <hip/hip_bf16.h>
#include <stdint.h>

// Problem constants (fixed by the reference)
#define M_ROWS 4096   // B
#define N_COLS 8192   // N
#define KDIM   512    // D

// GEMM: 256x256 tile, 8 waves (2M x 4N), BK=32 K-tiles, 4-deep LDS ring
#define BM 256
#define BN 256
#define BKT 32
#define NKT (KDIM / BKT)   // 16 K-tiles
#define GTHREADS 512

typedef __attribute__((ext_vector_type(8))) __bf16 bf16x8;
typedef __attribute__((ext_vector_type(4))) float  f32x4;

// compiler-only fence + hw barrier (raw: no implicit vmcnt(0) drain)
#define BAR() do { asm volatile("" ::: "memory"); \
                   __builtin_amdgcn_s_barrier();  \
                   asm volatile("" ::: "memory"); } while (0)

// ---------- fp32 -> bf16 (RNE) ----------
__device__ __forceinline__ unsigned short f2bf(float f) {
  union { float f; uint32_t u; } v; v.f = f;
  uint32_t u = v.u;
  u += 0x7fffu + ((u >> 16) & 1u);
  return (unsigned short)(u >> 16);
}

// ---------- fused prep: cvt A,S to bf16 + positive scan + fp32 dot ----------
// grid = 4096 blocks x 256 thr; block b: convert slice of A||S, then scan
// onehot row b and compute s_pos[b] in fp32.
__global__ void prep_kernel(const float* __restrict__ A,
                            const float* __restrict__ S,
                            const int* __restrict__ onehot,
                            float* __restrict__ s_pos,
                            unsigned short* __restrict__ Abf,
                            unsigned short* __restrict__ Sbf) {
  const int b = blockIdx.x;
  const int tid = threadIdx.x;

  // --- cvt slice: 384 float4 per block (A: 524288 f4, S: 1048576 f4) ---
  #pragma unroll
  for (int i = 0; i < 2; ++i) {
    int li = tid + i * 256;
    if (li < 384) {
      int idx = b * 384 + li;
      float4 v; ushort4 o;
      if (idx < 524288) {
        v = reinterpret_cast<const float4*>(A)[idx];
        o.x = f2bf(v.x); o.y = f2bf(v.y); o.z = f2bf(v.z); o.w = f2bf(v.w);
        reinterpret_cast<ushort4*>(Abf)[idx] = o;
      } else {
        int k = idx - 524288;
        v = reinterpret_cast<const float4*>(S)[k];
        o.x = f2bf(v.x); o.y = f2bf(v.y); o.z = f2bf(v.z); o.w = f2bf(v.w);
        reinterpret_cast<ushort4*>(Sbf)[k] = o;
      }
    }
  }

  // --- positive scan (one-hot, exactly one nonzero per row) ---
  __shared__ int pos_s;
  if (tid == 0) pos_s = 0;
  __syncthreads();
  const int4* row = reinterpret_cast<const int4*>(onehot + (size_t)b * N_COLS);
  for (int i = tid; i < N_COLS / 4; i += 256) {
    int4 v = row[i];
    if (v.x | v.y | v.z | v.w) {
      int j = i * 4 + (v.x ? 0 : (v.y ? 1 : (v.z ? 2 : 3)));
      pos_s = j;
    }
  }
  __syncthreads();
  const int j = pos_s;

  // --- fp32 dot anchor[b] . sample[j] ---
  float sum = 0.f;
  const float* a = A + (size_t)b * KDIM;
  const float* s = S + (size_t)j * KDIM;
  for (int d = tid; d < KDIM; d += 256) sum += a[d] * s[d];
  #pragma unroll
  for (int off = 32; off > 0; off >>= 1) sum += __shfl_down(sum, off, 64);
  __shared__ float wsum[4];
  const int wid = tid >> 6, lane = tid & 63;
  if (lane == 0) wsum[wid] = sum;
  __syncthreads();
  if (tid == 0) s_pos[b] = (wsum[0] + wsum[1]) + (wsum[2] + wsum[3]);
}

// ---------- GEMM helpers ----------
// LDS chunk layout: [256 rows][32 k] bf16 (16 KB), 64B rows. XOR-swizzle the
// 16B granule index: g_lds = g_src ^ x(r), x(r) = (r&3)^((r>>2)&3). Derivation:
// frag-read lanes 0-15 hit rows r..r+15 at one granule; even/odd rows split the
// 16-bank halves, x(r) spreads each half over 4 slots -> 2 lanes/bank (free).
__device__ __forceinline__ int swz_x(int r) { return (r & 3) ^ ((r >> 2) & 3); }

__device__ __forceinline__ bf16x8 lds_frag(const unsigned short* chunk, int r, int lk) {
  int g = lk ^ swz_x(r);
  return *reinterpret_cast<const bf16x8*>(chunk + r * 32 + g * 8);
}

// stage one 16KB chunk (256 rows x 32 k of one operand, K-tile tt).
// LDS dest is linear (wave-uniform base + lane*16); the swizzle is applied by
// permuting the per-lane GLOBAL source granule (rule 21: both-sides-or-neither).
__device__ __forceinline__ void stage_chunk(const unsigned short* __restrict__ srcBase,
                                            int tt, unsigned short* chunk,
                                            int w, int l) {
  #pragma unroll
  for (int jj = 0; jj < 2; ++jj) {
    int r = jj * 128 + w * 16 + (l >> 2);          // row this lane's 16B lands in
    int g = (l & 3) ^ swz_x(r);                    // source k-granule
    const unsigned short* src = srcBase + (size_t)r * KDIM + tt * BKT + g * 8;
    __builtin_amdgcn_global_load_lds(
        (const __attribute__((address_space(1))) void*)src,
        (__attribute__((address_space(3))) void*)(chunk + jj * 4096 + w * 512),
        16, 0, 0);
  }
}

// one K-tile: 2 phases x {ds_read subtile, stage 1 chunk, BAR, 16 MFMA, BAR};
// counted vmcnt (8 steady / 4,0 tail) before the tile's closing barrier.
template<bool STAGE, int VM>
__device__ __forceinline__ void ktile(int t, unsigned short (*lds)[2][BM * BKT],
                                      const unsigned short* __restrict__ Abase,
                                      const unsigned short* __restrict__ Sbase,
                                      f32x4 (&acc)[8][4],
                                      int wr, int wc, int lr, int lk, int w, int l) {
  const unsigned short* cA = lds[t & 3][0];
  const unsigned short* cB = lds[t & 3][1];
  bf16x8 bfr[4], afr[4];
  // phase 0: B-frags (held both phases) + A-frags m=0..3; stage A-chunk of t+3
  #pragma unroll
  for (int n = 0; n < 4; ++n) bfr[n] = lds_frag(cB, wc * 64 + n * 16 + lr, lk);
  #pragma unroll
  for (int m = 0; m < 4; ++m) afr[m] = lds_frag(cA, wr * 128 + m * 16 + lr, lk);
  if (STAGE) stage_chunk(Abase, t + 3, lds[(t + 3) & 3][0], w, l);
  BAR();
  __builtin_amdgcn_s_setprio(1);
  #pragma unroll
  for (int m = 0; m < 4; ++m)
    #pragma unroll
    for (int n = 0; n < 4; ++n)
      acc[m][n] = __builtin_amdgcn_mfma_f32_16x16x32_bf16(afr[m], bfr[n],
                                                          acc[m][n], 0, 0, 0);
  __builtin_amdgcn_s_setprio(0);
  BAR();
  // phase 1: A-frags m=4..7; stage B-chunk of t+3
  #pragma unroll
  for (int m = 0; m < 4; ++m) afr[m] = lds_frag(cA, wr * 128 + (m + 4) * 16 + lr, lk);
  if (STAGE) stage_chunk(Sbase, t + 3, lds[(t + 3) & 3][1], w, l);
  BAR();
  __builtin_amdgcn_s_setprio(1);
  #pragma unroll
  for (int m = 0; m < 4; ++m)
    #pragma unroll
    for (int n = 0; n < 4; ++n)
      acc[m + 4][n] = __builtin_amdgcn_mfma_f32_16x16x32_bf16(afr[m], bfr[n],
                                                              acc[m + 4][n], 0, 0, 0);
  __builtin_amdgcn_s_setprio(0);
  // guarantee tile t+1's 4 staging loads have landed before the barrier that
  // precedes its reads; leave tiles t+2,t+3 (8 loads) in flight.
  if (VM == 8)      asm volatile("s_waitcnt vmcnt(8)" ::: "memory");
  else if (VM == 4) asm volatile("s_waitcnt vmcnt(4)" ::: "memory");
  else if (VM == 0) asm volatile("s_waitcnt vmcnt(0)" ::: "memory");
  BAR();
}

// ---------- bf16 MFMA GEMM, 256x256 tile, fused hinge-sum epilogue ----------
__global__ __launch_bounds__(GTHREADS, 2) void gemm_hinge_kernel(
    const unsigned short* __restrict__ Abf,
    const unsigned short* __restrict__ Sbf,
    const float* __restrict__ s_pos,
    double* __restrict__ partial) {
  __shared__ alignas(16) unsigned short lds[4][2][BM * BKT];  // 128 KB ring
  __shared__ float wred[8];

  const int t    = threadIdx.x;
  const int w    = t >> 6;          // wave 0..7
  const int lane = t & 63;
  const int wr   = w >> 2;          // 0..1  (wave M-block: 128 rows)
  const int wc   = w & 3;           // 0..3  (wave N-block: 64 cols)
  const int lr   = lane & 15;
  const int lk   = lane >> 4;       // k-granule 0..3
  const int bx   = blockIdx.x;      // 512 blocks
  const int rowBase = (bx & 15) * BM;
  const int colBase = (bx >> 4) * BN;

  const unsigned short* Abase = Abf + (size_t)rowBase * KDIM;
  const unsigned short* Sbase = Sbf + (size_t)colBase * KDIM;

  f32x4 acc[8][4];
  #pragma unroll
  for (int m = 0; m < 8; ++m)
    #pragma unroll
    for (int n = 0; n < 4; ++n)
      acc[m][n] = (f32x4){0.f, 0.f, 0.f, 0.f};

  // prologue: stage tiles 0,1,2 into ring slots 0,1,2 (12 loads/thread)
  #pragma unroll
  for (int tt = 0; tt < 3; ++tt) {
    stage_chunk(Abase, tt, lds[tt][0], w, lane);
    stage_chunk(Sbase, tt, lds[tt][1], w, lane);
  }
  asm volatile("s_waitcnt vmcnt(8)" ::: "memory");  // tile 0's 4 loads landed
  BAR();

  #pragma unroll 1
  for (int kt = 0; kt < NKT - 3; ++kt)              // t = 0..12, stage t+3
    ktile<true, 8>(kt, lds, Abase, Sbase, acc, wr, wc, lr, lk, w, lane);
  ktile<false, 4>(NKT - 3, lds, Abase, Sbase, acc, wr, wc, lr, lk, w, lane);
  ktile<false, 0>(NKT - 2, lds, Abase, Sbase, acc, wr, wc, lr, lk, w, lane);
  ktile<false, -1>(NKT - 1, lds, Abase, Sbase, acc, wr, wc, lr, lk, w, lane);

  // epilogue: hinge = max(s - s_pos[row] + 1, 0), one scalar per block.
  // C/D layout: col = lane&15, row = (lane>>4)*4 + reg (verified m89).
  float lsum = 0.f;
  const int rl = lk * 4;
  #pragma unroll
  for (int m = 0; m < 8; ++m) {
    float sp[4];
    #pragma unroll
    for (int r = 0; r < 4; ++r)
      sp[r] = s_pos[rowBase + wr * 128 + m * 16 + rl + r];
    #pragma unroll
    for (int n = 0; n < 4; ++n)
      #pragma unroll
      for (int r = 0; r < 4; ++r)
        lsum += fmaxf(acc[m][n][r] - sp[r] + 1.0f, 0.f);
  }
  #pragma unroll
  for (int off = 32; off > 0; off >>= 1) lsum += __shfl_down(lsum, off, 64);
  if (lane == 0) wred[w] = lsum;
  __syncthreads();
  if (t == 0) {
    float s = 0.f;
    #pragma unroll
    for (int i = 0; i < 8; ++i) s += wred[i];
    partial[bx] = (double)s;
  }
}

// ---------- deterministic final reduction (512 partials) ----------
__global__ void finalize_kernel(const double* __restrict__ partial,
                                float* __restrict__ out) {
  __shared__ double sdata[256];
  double s = 0.0;
  for (int i = threadIdx.x; i < 512; i += 256) s += partial[i];
  sdata[threadIdx.x] = s;
  __syncthreads();
  for (int st = 128; st > 0; st >>= 1) {
    if (threadIdx.x < st) sdata[threadIdx.x] += sdata[threadIdx.x + st];
    __syncthreads();
  }
  if (threadIdx.x == 0) {
    // positive entry contributes exactly 1 per row -> subtract B
    double v = (sdata[0] - (double)M_ROWS) / ((double)M_ROWS * (double)(N_COLS - 1));
    *out = (float)v;
  }
}

extern "C" void kernel_launch(void* const* d_in, const int* in_sizes, int n_in,
                              void* d_out, int out_size, void* d_ws, size_t ws_size,
                              hipStream_t stream) {
  const float* A  = (const float*)d_in[0];   // anchor [4096,512] f32
  const float* S  = (const float*)d_in[1];   // sample [8192,512] f32
  const int*   oh = (const int*)d_in[2];     // one-hot [4096,8192] int
  float* out = (float*)d_out;

  // workspace layout (~12.1 MB): partials | s_pos | A_bf16 | S_bf16
  char* ws = (char*)d_ws;
  double* partial = (double*)ws;                           // 512 * 8B
  float* s_pos    = (float*)(ws + 16384);                  // 4096 * 4B
  unsigned short* Abf = (unsigned short*)(ws + 32768);     // 4 MB
  unsigned short* Sbf = Abf + (size_t)M_ROWS * KDIM;       // 8 MB

  prep_kernel<<<M_ROWS, 256, 0, stream>>>(A, S, oh, s_pos, Abf, Sbf);
  gemm_hinge_kernel<<<512, GTHREADS, 0, stream>>>(Abf, Sbf, s_pos, partial);
  finalize_kernel<<<1, 256, 0, stream>>>(partial, out);
}